// Round 1
// baseline (610.170 us; speedup 1.0000x reference)
//
#include <hip/hip_runtime.h>
#include <math.h>

#define BB 64
#define TT 2048
#define DD 768
#define PP 1024
#define KK 8
#define TSPLIT 16
#define TCHUNK (TT / TSPLIT)   // 128
#define D4 (DD / 4)            // 192

// ---------------------------------------------------------------------------
// ws layout (float units):
//   partial : [TSPLIT][BB][DD] = 786432
//   xmean   : [BB][DD]         = 49152
//   xproj   : [BB][DD]         = 49152
//   xscale  : [BB]             = 64
//   pscale  : [PP]             = 1024
//   sim     : [BB][PP]         = 65536
//   counts  : [PP]  (int)      = 1024
//   major   : [KK]  (int)      = 8
// total ~3.63 MB
// ---------------------------------------------------------------------------

__device__ __forceinline__ float wave_sum(float v) {
    for (int off = 32; off > 0; off >>= 1) v += __shfl_down(v, off, 64);
    return v;
}

// K1: partial max over token chunks.  grid (TSPLIT, BB), block 192.
__global__ __launch_bounds__(192) void k_maxpart(const float* __restrict__ x,
                                                 float* __restrict__ partial) {
    const int chunk = blockIdx.x, b = blockIdx.y, d4 = threadIdx.x;
    const float4* x4 = (const float4*)x;
    size_t base = ((size_t)b * TT + (size_t)chunk * TCHUNK) * D4 + d4;
    float4 m = make_float4(-INFINITY, -INFINITY, -INFINITY, -INFINITY);
    for (int t = 0; t < TCHUNK; ++t) {
        float4 v = x4[base + (size_t)t * D4];
        m.x = fmaxf(m.x, v.x); m.y = fmaxf(m.y, v.y);
        m.z = fmaxf(m.z, v.z); m.w = fmaxf(m.w, v.w);
    }
    ((float4*)partial)[((size_t)chunk * BB + b) * D4 + d4] = m;
}

// K2: reduce the 16 partials.  grid 48, block 256 (48*256 == BB*D4).
__global__ __launch_bounds__(256) void k_maxfinal(const float* __restrict__ partial,
                                                  float* __restrict__ xmean) {
    const int i = blockIdx.x * 256 + threadIdx.x;   // float4 index over BB*D4
    const float4* p4 = (const float4*)partial;
    float4 m = p4[i];
    for (int c = 1; c < TSPLIT; ++c) {
        float4 v = p4[(size_t)c * (BB * D4) + i];
        m.x = fmaxf(m.x, v.x); m.y = fmaxf(m.y, v.y);
        m.z = fmaxf(m.z, v.z); m.w = fmaxf(m.w, v.w);
    }
    ((float4*)xmean)[i] = m;
}

// prompt row scales: 1 wave per row.  grid PP/4, block 256.
__global__ __launch_bounds__(256) void k_pscale(const float* __restrict__ prompt,
                                                float* __restrict__ pscale) {
    const int p = blockIdx.x * 4 + (threadIdx.x >> 6);
    const int lane = threadIdx.x & 63;
    const float4* r = (const float4*)(prompt + (size_t)p * DD);
    float ss = 0.f;
    for (int j = 0; j < 3; ++j) {
        float4 v = r[j * 64 + lane];
        ss += v.x * v.x + v.y * v.y + v.z * v.z + v.w * v.w;
    }
    ss = wave_sum(ss);
    if (lane == 0) pscale[p] = 1.0f / sqrtf(fmaxf(ss, 1e-12f));
}

// x_proj = xmean @ W^T.  One wave per output o, lanes coalesced over K.
// grid (4, BB), block 256 (4 waves, 48 outputs each).
__global__ __launch_bounds__(256) void k_proj(const float* __restrict__ xmean,
                                              const float* __restrict__ W,
                                              float* __restrict__ xproj) {
    __shared__ float xm[DD];
    const int b = blockIdx.y;
    const int o0 = blockIdx.x * 192;
    for (int i = threadIdx.x; i < DD; i += 256) xm[i] = xmean[b * DD + i];
    __syncthreads();
    const int wave = threadIdx.x >> 6, lane = threadIdx.x & 63;
    const float4* xm4 = (const float4*)xm;
    for (int k = 0; k < 48; ++k) {
        const int o = o0 + 4 * k + wave;
        const float4* w4 = (const float4*)(W + (size_t)o * DD);
        float acc = 0.f;
        for (int j = 0; j < 3; ++j) {
            float4 a = xm4[j * 64 + lane];
            float4 w = w4[j * 64 + lane];
            acc += a.x * w.x + a.y * w.y + a.z * w.z + a.w * w.w;
        }
        acc = wave_sum(acc);
        if (lane == 0) xproj[b * DD + o] = acc;
    }
}

// x row scales: 1 wave per row.  grid BB/4, block 256.
__global__ __launch_bounds__(256) void k_xscale(const float* __restrict__ xproj,
                                                float* __restrict__ xscale) {
    const int b = blockIdx.x * 4 + (threadIdx.x >> 6);
    const int lane = threadIdx.x & 63;
    const float4* r = (const float4*)(xproj + (size_t)b * DD);
    float ss = 0.f;
    for (int j = 0; j < 3; ++j) {
        float4 v = r[j * 64 + lane];
        ss += v.x * v.x + v.y * v.y + v.z * v.z + v.w * v.w;
    }
    ss = wave_sum(ss);
    if (lane == 0) xscale[b] = 1.0f / sqrtf(fmaxf(ss, 1e-12f));
}

// sim[b,p] = dot(xproj[b], prompt[p]) * xscale[b] * pscale[p].
// grid (8, BB), block 256 (4 waves, 32 p's each).
__global__ __launch_bounds__(256) void k_sim(const float* __restrict__ xproj,
                                             const float* __restrict__ prompt,
                                             const float* __restrict__ xscale,
                                             const float* __restrict__ pscale,
                                             float* __restrict__ sim) {
    __shared__ float xp[DD];
    const int b = blockIdx.y;
    const int p0 = blockIdx.x * 128;
    for (int i = threadIdx.x; i < DD; i += 256) xp[i] = xproj[b * DD + i];
    __syncthreads();
    const int wave = threadIdx.x >> 6, lane = threadIdx.x & 63;
    const float xs = xscale[b];
    const float4* xp4 = (const float4*)xp;
    for (int k = 0; k < 32; ++k) {
        const int p = p0 + 4 * k + wave;
        const float4* pr4 = (const float4*)(prompt + (size_t)p * DD);
        float acc = 0.f;
        for (int j = 0; j < 3; ++j) {
            float4 a = xp4[j * 64 + lane];
            float4 v = pr4[j * 64 + lane];
            acc += a.x * v.x + a.y * v.y + a.z * v.z + a.w * v.w;
        }
        acc = wave_sum(acc);
        if (lane == 0) sim[b * PP + p] = acc * xs * pscale[p];
    }
}

// order-preserving float->uint map (total order, matches float compare for non-NaN)
__device__ __forceinline__ unsigned int fmap(float f) {
    unsigned int b = __float_as_uint(f);
    return (b & 0x80000000u) ? ~b : (b | 0x80000000u);
}

// per-row top-8 (ties -> lowest index), then bincount via atomics.  grid BB, block 256.
__global__ __launch_bounds__(256) void k_topk_rows(const float* __restrict__ sim,
                                                   int* __restrict__ counts) {
    __shared__ unsigned long long keys[PP];
    __shared__ unsigned long long wmax[4];
    __shared__ int sel[KK];
    const int b = blockIdx.x, tid = threadIdx.x;
    const int lane = tid & 63, wave = tid >> 6;
    for (int p = tid; p < PP; p += 256) {
        unsigned long long k = ((unsigned long long)fmap(sim[b * PP + p]) << 32)
                             | (unsigned int)(PP - 1 - p);
        keys[p] = k;
    }
    __syncthreads();
    for (int it = 0; it < KK; ++it) {
        unsigned long long mk = 0;
        for (int p = tid; p < PP; p += 256) {
            unsigned long long v = keys[p];
            if (v > mk) mk = v;
        }
        for (int off = 32; off > 0; off >>= 1) {
            unsigned long long o = __shfl_down(mk, off, 64);
            if (o > mk) mk = o;
        }
        if (lane == 0) wmax[wave] = mk;
        __syncthreads();
        if (tid == 0) {
            unsigned long long m = wmax[0];
            for (int w = 1; w < 4; ++w) if (wmax[w] > m) m = wmax[w];
            int p = PP - 1 - (int)(m & 0xFFFFFFFFu);
            sel[it] = p;
            keys[p] = 0ull;   // remove from next rounds
        }
        __syncthreads();
    }
    if (tid < KK) atomicAdd(&counts[sel[tid]], 1);
}

// top-8 of counts (ties -> lowest id), ordered.  grid 1, block 256.
__global__ __launch_bounds__(256) void k_topk_counts(const int* __restrict__ counts,
                                                     int* __restrict__ major) {
    __shared__ unsigned long long keys[PP];
    __shared__ unsigned long long wmax[4];
    const int tid = threadIdx.x;
    const int lane = tid & 63, wave = tid >> 6;
    for (int p = tid; p < PP; p += 256)
        keys[p] = ((unsigned long long)(unsigned int)counts[p] << 32)
                | (unsigned int)(PP - 1 - p);
    __syncthreads();
    for (int it = 0; it < KK; ++it) {
        unsigned long long mk = 0;
        for (int p = tid; p < PP; p += 256) {
            unsigned long long v = keys[p];
            if (v > mk) mk = v;
        }
        for (int off = 32; off > 0; off >>= 1) {
            unsigned long long o = __shfl_down(mk, off, 64);
            if (o > mk) mk = o;
        }
        if (lane == 0) wmax[wave] = mk;
        __syncthreads();
        if (tid == 0) {
            unsigned long long m = wmax[0];
            for (int w = 1; w < 4; ++w) if (wmax[w] > m) m = wmax[w];
            int p = PP - 1 - (int)(m & 0xFFFFFFFFu);
            major[it] = p;
            keys[p] = 0ull;
        }
        __syncthreads();
    }
}

// outputs: d_out[0] = reduce_sim, d_out[1..] = batched_prompt [BB][KK][DD].
// grid BB*KK + 1, block 192.
__global__ __launch_bounds__(192) void k_out(const float* __restrict__ prompt,
                                             const float* __restrict__ sim,
                                             const int* __restrict__ major,
                                             float* __restrict__ out) {
    if (blockIdx.x < BB * KK) {
        const int b = blockIdx.x >> 3, k = blockIdx.x & 7;
        const int id = major[k];
        const float* src = prompt + (size_t)id * DD;
        float* dst = out + 1 + ((size_t)(b * KK + k)) * DD;
        for (int i = threadIdx.x; i < DD; i += 192) dst[i] = src[i];
    } else {
        __shared__ float wsum[3];
        float s = 0.f;
        for (int i = threadIdx.x; i < BB * KK; i += 192) {
            const int b = i >> 3, k = i & 7;
            s += sim[b * PP + major[k]];
        }
        s = wave_sum(s);
        const int lane = threadIdx.x & 63, wave = threadIdx.x / 64;
        if (lane == 0) wsum[wave] = s;
        __syncthreads();
        if (threadIdx.x == 0) out[0] = (wsum[0] + wsum[1] + wsum[2]) / (float)BB;
    }
}

extern "C" void kernel_launch(void* const* d_in, const int* in_sizes, int n_in,
                              void* d_out, int out_size, void* d_ws, size_t ws_size,
                              hipStream_t stream) {
    const float* x      = (const float*)d_in[0];   // [64,2048,768]
    const float* prompt = (const float*)d_in[1];   // [1024,768]
    const float* W      = (const float*)d_in[2];   // [768,768]
    float* out = (float*)d_out;

    float* ws      = (float*)d_ws;
    float* partial = ws;                           // 786432
    float* xmean   = partial + TSPLIT * BB * DD;   // 49152
    float* xproj   = xmean + BB * DD;              // 49152
    float* xscale  = xproj + BB * DD;              // 64
    float* pscale  = xscale + BB;                  // 1024
    float* sim     = pscale + PP;                  // 65536
    int*   counts  = (int*)(sim + BB * PP);        // 1024
    int*   major   = counts + PP;                  // 8

    hipMemsetAsync(counts, 0, PP * sizeof(int), stream);

    k_maxpart<<<dim3(TSPLIT, BB), 192, 0, stream>>>(x, partial);
    k_maxfinal<<<48, 256, 0, stream>>>(partial, xmean);
    k_pscale<<<PP / 4, 256, 0, stream>>>(prompt, pscale);
    k_proj<<<dim3(4, BB), 256, 0, stream>>>(xmean, W, xproj);
    k_xscale<<<BB / 4, 256, 0, stream>>>(xproj, xscale);
    k_sim<<<dim3(8, BB), 256, 0, stream>>>(xproj, prompt, xscale, pscale, sim);
    k_topk_rows<<<BB, 256, 0, stream>>>(sim, counts);
    k_topk_counts<<<1, 256, 0, stream>>>(counts, major);
    k_out<<<BB * KK + 1, 192, 0, stream>>>(prompt, sim, major, out);
}

// Round 2
// 609.664 us; speedup vs baseline: 1.0008x; 1.0008x over previous
//
#include <hip/hip_runtime.h>
#include <math.h>

#define BB 64
#define TT 2048
#define DD 768
#define PP 1024
#define KK 8
#define TSPLIT 32
#define TCHUNK (TT / TSPLIT)   // 64
#define D4 (DD / 4)            // 192

// ---------------------------------------------------------------------------
// ws layout (4-byte units) — first region is zero-initialized by k_init:
//   xmean_enc : uint [BB*DD]  = 49152   (order-preserving encoded max)
//   xss       : float[BB]     = 64      (sum of squares of xproj row)
//   counts    : int  [PP]     = 1024
//   --- end zero region (50240 words) ---
//   pscale    : float[PP]     = 1024
//   sim       : float[BB*PP]  = 65536
//   major     : int  [KK]     = 8
//   xproj     : float[BB*DD]  = 49152
// ---------------------------------------------------------------------------
#define NZERO (BB * DD + BB + PP)

__device__ __forceinline__ float wave_sum(float v) {
    for (int off = 32; off > 0; off >>= 1) v += __shfl_down(v, off, 64);
    return v;
}

// order-preserving float->uint map (monotone for all non-NaN floats)
__device__ __forceinline__ unsigned int fmap(float f) {
    unsigned int b = __float_as_uint(f);
    return (b & 0x80000000u) ? ~b : (b | 0x80000000u);
}
__device__ __forceinline__ float funmap(unsigned int e) {
    return __uint_as_float((e & 0x80000000u) ? (e ^ 0x80000000u) : ~e);
}

// K1: zero-init the atomic region + prompt row scales.  grid 256, block 256.
__global__ __launch_bounds__(256) void k_init_pscale(const float* __restrict__ prompt,
                                                     unsigned int* __restrict__ zero_region,
                                                     float* __restrict__ pscale) {
    const int tid = threadIdx.x, blk = blockIdx.x;
    for (int i = blk * 256 + tid; i < NZERO; i += 256 * 256) zero_region[i] = 0u;
    const int p = blk * 4 + (tid >> 6);
    const int lane = tid & 63;
    const float4* r = (const float4*)(prompt + (size_t)p * DD);
    float ss = 0.f;
    for (int j = 0; j < 3; ++j) {
        float4 v = r[j * 64 + lane];
        ss += v.x * v.x + v.y * v.y + v.z * v.z + v.w * v.w;
    }
    ss = wave_sum(ss);
    if (lane == 0) pscale[p] = 1.0f / sqrtf(fmaxf(ss, 1e-12f));
}

// K2: single-pass token max via encoded atomicMax.  grid (TSPLIT, BB), block 192.
__global__ __launch_bounds__(192) void k_maxpart(const float* __restrict__ x,
                                                 unsigned int* __restrict__ xmean_enc) {
    const int chunk = blockIdx.x, b = blockIdx.y, d4 = threadIdx.x;
    const float4* x4 = (const float4*)x;
    size_t base = ((size_t)b * TT + (size_t)chunk * TCHUNK) * D4 + d4;
    float4 m = make_float4(-INFINITY, -INFINITY, -INFINITY, -INFINITY);
    #pragma unroll 8
    for (int t = 0; t < TCHUNK; ++t) {
        float4 v = x4[base + (size_t)t * D4];
        m.x = fmaxf(m.x, v.x); m.y = fmaxf(m.y, v.y);
        m.z = fmaxf(m.z, v.z); m.w = fmaxf(m.w, v.w);
    }
    unsigned int* dst = xmean_enc + (size_t)b * DD + d4 * 4;
    atomicMax(dst + 0, fmap(m.x));
    atomicMax(dst + 1, fmap(m.y));
    atomicMax(dst + 2, fmap(m.z));
    atomicMax(dst + 3, fmap(m.w));
}

// K3: x_proj = xmean @ W^T, plus row sum-of-squares into xss.
// grid (4, BB), block 256 (4 waves, 48 outputs each).
__global__ __launch_bounds__(256) void k_proj(const unsigned int* __restrict__ xmean_enc,
                                              const float* __restrict__ W,
                                              float* __restrict__ xproj,
                                              float* __restrict__ xss) {
    __shared__ float xm[DD];
    __shared__ float wss[4];
    const int b = blockIdx.y;
    const int o0 = blockIdx.x * 192;
    for (int i = threadIdx.x; i < DD; i += 256) xm[i] = funmap(xmean_enc[b * DD + i]);
    __syncthreads();
    const int wave = threadIdx.x >> 6, lane = threadIdx.x & 63;
    const float4* xm4 = (const float4*)xm;
    float sacc = 0.f;
    for (int k = 0; k < 48; ++k) {
        const int o = o0 + 4 * k + wave;
        const float4* w4 = (const float4*)(W + (size_t)o * DD);
        float acc = 0.f;
        for (int j = 0; j < 3; ++j) {
            float4 a = xm4[j * 64 + lane];
            float4 w = w4[j * 64 + lane];
            acc += a.x * w.x + a.y * w.y + a.z * w.z + a.w * w.w;
        }
        acc = wave_sum(acc);
        if (lane == 0) {
            xproj[b * DD + o] = acc;
            sacc += acc * acc;
        }
    }
    if (lane == 0) wss[wave] = sacc;
    __syncthreads();
    if (threadIdx.x == 0)
        atomicAdd(&xss[b], wss[0] + wss[1] + wss[2] + wss[3]);
}

// K4: sim[b,p] = dot(xproj[b], prompt[p]) * rsqrt(xss[b]) * pscale[p].
// grid (8, BB), block 256 (4 waves, 32 p's each).
__global__ __launch_bounds__(256) void k_sim(const float* __restrict__ xproj,
                                             const float* __restrict__ prompt,
                                             const float* __restrict__ xss,
                                             const float* __restrict__ pscale,
                                             float* __restrict__ sim) {
    __shared__ float xp[DD];
    const int b = blockIdx.y;
    const int p0 = blockIdx.x * 128;
    for (int i = threadIdx.x; i < DD; i += 256) xp[i] = xproj[b * DD + i];
    __syncthreads();
    const int wave = threadIdx.x >> 6, lane = threadIdx.x & 63;
    const float xs = 1.0f / sqrtf(fmaxf(xss[b], 1e-12f));
    const float4* xp4 = (const float4*)xp;
    for (int k = 0; k < 32; ++k) {
        const int p = p0 + 4 * k + wave;
        const float4* pr4 = (const float4*)(prompt + (size_t)p * DD);
        float acc = 0.f;
        for (int j = 0; j < 3; ++j) {
            float4 a = xp4[j * 64 + lane];
            float4 v = pr4[j * 64 + lane];
            acc += a.x * v.x + a.y * v.y + a.z * v.z + a.w * v.w;
        }
        acc = wave_sum(acc);
        if (lane == 0) sim[b * PP + p] = acc * xs * pscale[p];
    }
}

// K5: per-row top-8 (ties -> lowest index), then bincount via atomics.  grid BB, block 256.
__global__ __launch_bounds__(256) void k_topk_rows(const float* __restrict__ sim,
                                                   int* __restrict__ counts) {
    __shared__ unsigned long long keys[PP];
    __shared__ unsigned long long wmax[4];
    __shared__ int sel[KK];
    const int b = blockIdx.x, tid = threadIdx.x;
    const int lane = tid & 63, wave = tid >> 6;
    for (int p = tid; p < PP; p += 256) {
        unsigned long long k = ((unsigned long long)fmap(sim[b * PP + p]) << 32)
                             | (unsigned int)(PP - 1 - p);
        keys[p] = k;
    }
    __syncthreads();
    for (int it = 0; it < KK; ++it) {
        unsigned long long mk = 0;
        for (int p = tid; p < PP; p += 256) {
            unsigned long long v = keys[p];
            if (v > mk) mk = v;
        }
        for (int off = 32; off > 0; off >>= 1) {
            unsigned long long o = __shfl_down(mk, off, 64);
            if (o > mk) mk = o;
        }
        if (lane == 0) wmax[wave] = mk;
        __syncthreads();
        if (tid == 0) {
            unsigned long long m = wmax[0];
            for (int w = 1; w < 4; ++w) if (wmax[w] > m) m = wmax[w];
            int p = PP - 1 - (int)(m & 0xFFFFFFFFu);
            sel[it] = p;
            keys[p] = 0ull;
        }
        __syncthreads();
    }
    if (tid < KK) atomicAdd(&counts[sel[tid]], 1);
}

// K6: top-8 of counts (ties -> lowest id), ordered.  grid 1, block 256.
__global__ __launch_bounds__(256) void k_topk_counts(const int* __restrict__ counts,
                                                     int* __restrict__ major) {
    __shared__ unsigned long long keys[PP];
    __shared__ unsigned long long wmax[4];
    const int tid = threadIdx.x;
    const int lane = tid & 63, wave = tid >> 6;
    for (int p = tid; p < PP; p += 256)
        keys[p] = ((unsigned long long)(unsigned int)counts[p] << 32)
                | (unsigned int)(PP - 1 - p);
    __syncthreads();
    for (int it = 0; it < KK; ++it) {
        unsigned long long mk = 0;
        for (int p = tid; p < PP; p += 256) {
            unsigned long long v = keys[p];
            if (v > mk) mk = v;
        }
        for (int off = 32; off > 0; off >>= 1) {
            unsigned long long o = __shfl_down(mk, off, 64);
            if (o > mk) mk = o;
        }
        if (lane == 0) wmax[wave] = mk;
        __syncthreads();
        if (tid == 0) {
            unsigned long long m = wmax[0];
            for (int w = 1; w < 4; ++w) if (wmax[w] > m) m = wmax[w];
            int p = PP - 1 - (int)(m & 0xFFFFFFFFu);
            major[it] = p;
            keys[p] = 0ull;
        }
        __syncthreads();
    }
}

// K7: outputs.  d_out[0] = reduce_sim, d_out[1..] = batched_prompt [BB][KK][DD].
// grid BB*KK + 1, block 192.
__global__ __launch_bounds__(192) void k_out(const float* __restrict__ prompt,
                                             const float* __restrict__ sim,
                                             const int* __restrict__ major,
                                             float* __restrict__ out) {
    if (blockIdx.x < BB * KK) {
        const int b = blockIdx.x >> 3, k = blockIdx.x & 7;
        const int id = major[k];
        const float* src = prompt + (size_t)id * DD;
        float* dst = out + 1 + ((size_t)(b * KK + k)) * DD;
        for (int i = threadIdx.x; i < DD; i += 192) dst[i] = src[i];
    } else {
        __shared__ float wsum[3];
        float s = 0.f;
        for (int i = threadIdx.x; i < BB * KK; i += 192) {
            const int b = i >> 3, k = i & 7;
            s += sim[b * PP + major[k]];
        }
        s = wave_sum(s);
        const int lane = threadIdx.x & 63, wave = threadIdx.x / 64;
        if (lane == 0) wsum[wave] = s;
        __syncthreads();
        if (threadIdx.x == 0) out[0] = (wsum[0] + wsum[1] + wsum[2]) / (float)BB;
    }
}

extern "C" void kernel_launch(void* const* d_in, const int* in_sizes, int n_in,
                              void* d_out, int out_size, void* d_ws, size_t ws_size,
                              hipStream_t stream) {
    const float* x      = (const float*)d_in[0];   // [64,2048,768]
    const float* prompt = (const float*)d_in[1];   // [1024,768]
    const float* W      = (const float*)d_in[2];   // [768,768]
    float* out = (float*)d_out;

    unsigned int* ws        = (unsigned int*)d_ws;
    unsigned int* xmean_enc = ws;                            // 49152
    float*        xss       = (float*)(xmean_enc + BB * DD); // 64
    int*          counts    = (int*)(xss + BB);              // 1024
    float*        pscale    = (float*)(counts + PP);         // 1024
    float*        sim       = pscale + PP;                   // 65536
    int*          major     = (int*)(sim + BB * PP);         // 8
    float*        xproj     = (float*)(major + KK);          // 49152

    k_init_pscale<<<256, 256, 0, stream>>>(prompt, ws, pscale);
    k_maxpart<<<dim3(TSPLIT, BB), 192, 0, stream>>>(x, xmean_enc);
    k_proj<<<dim3(4, BB), 256, 0, stream>>>(xmean_enc, W, xproj, xss);
    k_sim<<<dim3(8, BB), 256, 0, stream>>>(xproj, prompt, xss, pscale, sim);
    k_topk_rows<<<BB, 256, 0, stream>>>(sim, counts);
    k_topk_counts<<<1, 256, 0, stream>>>(counts, major);
    k_out<<<BB * KK + 1, 192, 0, stream>>>(prompt, sim, major, out);
}